// Round 4
// baseline (8679.839 us; speedup 1.0000x reference)
//
#include <hip/hip_runtime.h>

// Problem constants (match reference)
#define TT 4096   // sequence length (torch "batch" acting as time)
#define SD 64     // shared features
#define PD 8      // per-device features
#define DD 32     // devices
#define HH 128    // hidden
#define NG 512    // 4*H gate rows
#define XD 72     // S+P
#define XPAIRS 36 // packed f16x2 pairs of x
#define WROW 37   // padded row stride (uints) for W_ih0 in LDS (fallback path)
#define GXTB 16   // t-tile of the gx precompute kernel

typedef _Float16 h2 __attribute__((ext_vector_type(2)));
typedef unsigned uv16 __attribute__((ext_vector_type(16)));
typedef unsigned uv4 __attribute__((ext_vector_type(4)));

#if defined(__has_builtin)
#  if __has_builtin(__builtin_amdgcn_fdot2)
#    define USE_DOT2 1
#  endif
#endif

// ---- X-macro machinery: 64 indices, and 16 quads (group, 4 indices) ----
#define LIST64(X) \
  X(0) X(1) X(2) X(3) X(4) X(5) X(6) X(7) \
  X(8) X(9) X(10) X(11) X(12) X(13) X(14) X(15) \
  X(16) X(17) X(18) X(19) X(20) X(21) X(22) X(23) \
  X(24) X(25) X(26) X(27) X(28) X(29) X(30) X(31) \
  X(32) X(33) X(34) X(35) X(36) X(37) X(38) X(39) \
  X(40) X(41) X(42) X(43) X(44) X(45) X(46) X(47) \
  X(48) X(49) X(50) X(51) X(52) X(53) X(54) X(55) \
  X(56) X(57) X(58) X(59) X(60) X(61) X(62) X(63)

#define QUADS16(X) \
  X(0,0,1,2,3)     X(1,4,5,6,7)     X(2,8,9,10,11)   X(3,12,13,14,15) \
  X(4,16,17,18,19) X(5,20,21,22,23) X(6,24,25,26,27) X(7,28,29,30,31) \
  X(8,32,33,34,35) X(9,36,37,38,39) X(10,40,41,42,43) X(11,44,45,46,47) \
  X(12,48,49,50,51) X(13,52,53,54,55) X(14,56,57,58,59) X(15,60,61,62,63)

// pack two floats into one uint of f16x2 (a = low element), RTE
__device__ __forceinline__ unsigned pack_h2(float a, float b) {
  unsigned short ua = __builtin_bit_cast(unsigned short, (_Float16)a);
  unsigned short ub = __builtin_bit_cast(unsigned short, (_Float16)b);
  return ((unsigned)ub << 16) | ua;
}
__device__ __forceinline__ unsigned short f16bits(float a) {
  return __builtin_bit_cast(unsigned short, (_Float16)a);
}
__device__ __forceinline__ float f16val(unsigned short u) {
  return (float)__builtin_bit_cast(_Float16, u);
}

// acc += dot(f16x2 w, f16x2 h), fp32 accumulate (v_dot2_f32_f16)
__device__ __forceinline__ float dot2(unsigned w, unsigned h, float acc) {
#ifdef USE_DOT2
  return __builtin_amdgcn_fdot2(__builtin_bit_cast(h2, w),
                                __builtin_bit_cast(h2, h), acc, false);
#else
  h2 wv = __builtin_bit_cast(h2, w), hv = __builtin_bit_cast(h2, h);
  return __builtin_fmaf((float)wv[1], (float)hv[1],
                        __builtin_fmaf((float)wv[0], (float)hv[0], acc));
#endif
}

__device__ __forceinline__ float fast_sigmoid(float x) {
  return 1.0f / (1.0f + __expf(-x));
}
__device__ __forceinline__ float fast_tanh(float x) {
  return 2.0f / (1.0f + __expf(-2.0f * x)) - 1.0f;
}

// ---------------------------------------------------------------------------
// gx precompute: gx[d][t][g] = f16( b0[d][g] + W_ih0[d][g][:] . x[d][t][:] )
// ---------------------------------------------------------------------------
__global__ __launch_bounds__(512)
void gx_kernel(const float* __restrict__ shared_in,  // [T, S]
               const float* __restrict__ perdev,     // [D, T, P]
               const float* __restrict__ Wih0,       // [D, 4H, S+P]
               const float* __restrict__ b0,         // [D, 4H]
               unsigned short* __restrict__ gx)      // [D, T, 4H] f16
{
  const int d = blockIdx.y;
  const int t0 = blockIdx.x * GXTB;
  const int g = threadIdx.x;

  __shared__ unsigned xs[GXTB * XPAIRS];  // x tile, packed f16x2

  const float* p = Wih0 + (size_t)(d * NG + g) * XD;
  uv16 w0, w1;
  uv4 w2;
#pragma unroll
  for (int j = 0; j < 16; ++j) w0[j] = pack_h2(p[2 * j], p[2 * j + 1]);
#pragma unroll
  for (int j = 0; j < 16; ++j) w1[j] = pack_h2(p[32 + 2 * j], p[33 + 2 * j]);
#pragma unroll
  for (int j = 0; j < 4; ++j) w2[j] = pack_h2(p[64 + 2 * j], p[65 + 2 * j]);
  const float b0g = b0[d * NG + g];

  for (int i = g; i < GXTB * XPAIRS; i += 512) {
    int r = i / XPAIRS, j = i - r * XPAIRS, t = t0 + r;
    float a, b;
    if (j < SD / 2) {
      a = shared_in[t * SD + 2 * j];
      b = shared_in[t * SD + 2 * j + 1];
    } else {
      int k = 2 * (j - SD / 2);
      a = perdev[((size_t)d * TT + t) * PD + k];
      b = perdev[((size_t)d * TT + t) * PD + k + 1];
    }
    xs[i] = pack_h2(a, b);
  }
  __syncthreads();

#define WJ(j) ((j) < 16 ? w0[(j)] : ((j) < 32 ? w1[(j)-16] : w2[(j)-32]))
  for (int tt = 0; tt < GXTB; ++tt) {
    const unsigned* xr = &xs[tt * XPAIRS];
    float a0 = b0g, a1 = 0.f, a2 = 0.f, a3 = 0.f;
#pragma unroll
    for (int j = 0; j < XPAIRS; j += 4) {
      a0 = dot2(WJ(j + 0), xr[j + 0], a0);
      a1 = dot2(WJ(j + 1), xr[j + 1], a1);
      a2 = dot2(WJ(j + 2), xr[j + 2], a2);
      a3 = dot2(WJ(j + 3), xr[j + 3], a3);
    }
    gx[((size_t)d * TT + t0 + tt) * NG + g] = f16bits((a0 + a1) + (a2 + a3));
  }
#undef WJ
}

// ---------------------------------------------------------------------------
// Main recurrence. Weights held as: W_hh0 -> 64 AGPRs (inline asm, guaranteed
// resident), W_ih1/W_hh1 -> 128 individual scalar VGPR values (no tuples ->
// no RA fragmentation -> no spill, the R2/R3 pathology).
// ---------------------------------------------------------------------------
template <bool PRE>
__global__ __launch_bounds__(512, 2)
void lstm_pd_kernel(const float* __restrict__ shared_in,   // [T, S]
                    const float* __restrict__ perdev,      // [D, T, P]
                    const float* __restrict__ Wih0,        // [D, 4H, S+P]
                    const float* __restrict__ Whh0,        // [D, 4H, H]
                    const float* __restrict__ b0,          // [D, 4H]
                    const float* __restrict__ Wih1,        // [D, 4H, H]
                    const float* __restrict__ Whh1,        // [D, 4H, H]
                    const float* __restrict__ b1,          // [D, 4H]
                    const float* __restrict__ Wout,        // [D, H]
                    const float* __restrict__ bout,        // [D]
                    const unsigned short* __restrict__ gx, // [D, T, 4H] f16 (PRE)
                    float* __restrict__ out)               // [T, D]
{
  const int d = blockIdx.x;        // device
  const int g = threadIdx.x;       // gate row 0..511
  const int lane = g & 63;
  const int wave = g >> 6;

  __shared__ float act0_s[NG];
  __shared__ float act1_s[NG];
  __shared__ __align__(16) unsigned h0_s[HH / 2];      // h0 packed f16x2
  __shared__ __align__(16) unsigned h1_s[HH / 2];      // h1 packed f16x2
  __shared__ __align__(16) unsigned x_s[PRE ? 4 : (XPAIRS + 4)];
  __shared__ unsigned wih0_s[PRE ? 1 : (NG * WROW)];
  __shared__ float part_s[2];

  // ---- weight registers ----
#define DWA(n) unsigned wa##n;
  LIST64(DWA)
#undef DWA
#define DWI(n) unsigned wi##n; unsigned wh##n;
  LIST64(DWI)
#undef DWI

  // W_hh0 row g -> AGPRs (write-once; read each step)
  {
    const float* pa = Whh0 + (size_t)(d * NG + g) * HH;
#define SWA(n) { unsigned tv = pack_h2(pa[2 * (n)], pa[2 * (n) + 1]); \
                 asm("v_accvgpr_write_b32 %0, %1" : "=a"(wa##n) : "v"(tv)); }
    LIST64(SWA)
#undef SWA
  }
  // W_ih1 / W_hh1 rows -> scalar VGPR values
  {
    const float* pi = Wih1 + (size_t)(d * NG + g) * HH;
    const float* ph = Whh1 + (size_t)(d * NG + g) * HH;
#define SWI(n) wi##n = pack_h2(pi[2 * (n)], pi[2 * (n) + 1]); \
               wh##n = pack_h2(ph[2 * (n)], ph[2 * (n) + 1]);
    LIST64(SWI)
#undef SWI
  }

  float b0g = 0.f;
  if (!PRE) {
    const float* p = Wih0 + (size_t)(d * NG + g) * XD;
    for (int j = 0; j < XPAIRS; ++j) wih0_s[g * WROW + j] = pack_h2(p[2 * j], p[2 * j + 1]);
    b0g = b0[d * NG + g];
  }
  const float b1g = b1[d * NG + g];
  const bool is_tanh_gate = ((g >> 7) == 2);  // rows 256..383 = candidate gate
  float c0 = 0.f, c1 = 0.f;
  const float woutu = (g < HH) ? Wout[d * HH + g] : 0.f;
  const float boutd = bout[d];

  if (g < HH / 2) { h0_s[g] = 0u; h1_s[g] = 0u; }

  // prefetch x-path for t=0
  unsigned short gxc = 0, gxn = 0;
  float xa = 0.f, xb = 0.f;
  if (PRE) {
    gxc = gx[((size_t)d * TT + 0) * NG + g];
  } else if (g < XPAIRS) {
    if (g < SD / 2) {
      xa = shared_in[0 * SD + 2 * g];
      xb = shared_in[0 * SD + 2 * g + 1];
    } else {
      int k = 2 * (g - SD / 2);
      xa = perdev[((size_t)d * TT + 0) * PD + k];
      xb = perdev[((size_t)d * TT + 0) * PD + k + 1];
    }
  }

  __syncthreads();

  for (int t = 0; t < TT; ++t) {
    if (!PRE) {
      if (g < XPAIRS) x_s[g] = pack_h2(xa, xb);
      __syncthreads();  // barrier 1 (fallback only)
    }

    // ---- phase 2: gates0[g] = gx + Whh0_row . h0 ----
    float a0, a1 = 0.f, a2 = 0.f, a3 = 0.f;
    if (PRE) {
      a0 = f16val(gxc);
    } else {
      a0 = b0g;
      const unsigned* wrow = &wih0_s[g * WROW];
#pragma unroll
      for (int j = 0; j < XPAIRS; j += 4) {
        a0 = dot2(wrow[j + 0], x_s[j + 0], a0);
        a1 = dot2(wrow[j + 1], x_s[j + 1], a1);
        a2 = dot2(wrow[j + 2], x_s[j + 2], a2);
        a3 = dot2(wrow[j + 3], x_s[j + 3], a3);
      }
    }
    {
      const uint4* h4 = (const uint4*)h0_s;
#define DA(q, n0, n1, n2, n3) { \
      uint4 hv = h4[q]; unsigned t0r, t1r, t2r, t3r; \
      asm("v_accvgpr_read_b32 %0, %1" : "=v"(t0r) : "a"(wa##n0)); \
      asm("v_accvgpr_read_b32 %0, %1" : "=v"(t1r) : "a"(wa##n1)); \
      asm("v_accvgpr_read_b32 %0, %1" : "=v"(t2r) : "a"(wa##n2)); \
      asm("v_accvgpr_read_b32 %0, %1" : "=v"(t3r) : "a"(wa##n3)); \
      a0 = dot2(t0r, hv.x, a0); a1 = dot2(t1r, hv.y, a1); \
      a2 = dot2(t2r, hv.z, a2); a3 = dot2(t3r, hv.w, a3); }
      QUADS16(DA)
#undef DA
      float pre = (a0 + a1) + (a2 + a3);
      act0_s[g] = is_tanh_gate ? fast_tanh(pre) : fast_sigmoid(pre);
    }
    __syncthreads();  // barrier 2

    // deferred output store for t-1
    if (g == 0 && t > 0) out[(size_t)(t - 1) * DD + d] = part_s[0] + part_s[1] + boutd;

    // prefetch x-path for t+1
    if (PRE) {
      if (t + 1 < TT) gxn = gx[((size_t)d * TT + t + 1) * NG + g];
    } else if (g < XPAIRS && t + 1 < TT) {
      int tn = t + 1;
      if (g < SD / 2) {
        xa = shared_in[tn * SD + 2 * g];
        xb = shared_in[tn * SD + 2 * g + 1];
      } else {
        int k = 2 * (g - SD / 2);
        xa = perdev[((size_t)d * TT + tn) * PD + k];
        xb = perdev[((size_t)d * TT + tn) * PD + k + 1];
      }
    }

    // ---- phase 3: layer-0 cell update (threads 0..127) ----
    if (g < HH) {
      float ig = act0_s[g], fg = act0_s[g + 128], gg = act0_s[g + 256], og = act0_s[g + 384];
      c0 = __builtin_fmaf(fg, c0, ig * gg);
      float h0n = og * fast_tanh(c0);
      ((unsigned short*)h0_s)[g] = f16bits(h0n);
    }
    __syncthreads();  // barrier 3

    // ---- phase 4: gates1[g] = b1 + Wih1_row . h0_new + Whh1_row . h1 ----
    a0 = b1g; a1 = 0.f; a2 = 0.f; a3 = 0.f;
    {
      const uint4* h4 = (const uint4*)h0_s;
#define DI(q, n0, n1, n2, n3) { \
      uint4 hv = h4[q]; \
      a0 = dot2(wi##n0, hv.x, a0); a1 = dot2(wi##n1, hv.y, a1); \
      a2 = dot2(wi##n2, hv.z, a2); a3 = dot2(wi##n3, hv.w, a3); }
      QUADS16(DI)
#undef DI
      const uint4* g4 = (const uint4*)h1_s;
#define DH(q, n0, n1, n2, n3) { \
      uint4 hv = g4[q]; \
      a0 = dot2(wh##n0, hv.x, a0); a1 = dot2(wh##n1, hv.y, a1); \
      a2 = dot2(wh##n2, hv.z, a2); a3 = dot2(wh##n3, hv.w, a3); }
      QUADS16(DH)
#undef DH
      float pre = (a0 + a1) + (a2 + a3);
      act1_s[g] = is_tanh_gate ? fast_tanh(pre) : fast_sigmoid(pre);
    }
    __syncthreads();  // barrier 4

    // ---- phase 5: layer-1 cell update + output partial (threads 0..127) ----
    if (g < HH) {
      float ig = act1_s[g], fg = act1_s[g + 128], gg = act1_s[g + 256], og = act1_s[g + 384];
      c1 = __builtin_fmaf(fg, c1, ig * gg);
      float h1n = og * fast_tanh(c1);
      ((unsigned short*)h1_s)[g] = f16bits(h1n);
      float p = woutu * h1n;
#pragma unroll
      for (int off = 32; off > 0; off >>= 1) p += __shfl_down(p, off, 64);
      if (lane == 0) part_s[wave] = p;
    }
    gxc = gxn;
  }

  __syncthreads();
  if (g == 0) out[(size_t)(TT - 1) * DD + d] = part_s[0] + part_s[1] + boutd;
}

extern "C" void kernel_launch(void* const* d_in, const int* in_sizes, int n_in,
                              void* d_out, int out_size, void* d_ws, size_t ws_size,
                              hipStream_t stream) {
  const float* shared_in = (const float*)d_in[0];
  const float* perdev    = (const float*)d_in[1];
  const float* Wih0      = (const float*)d_in[2];
  const float* Whh0      = (const float*)d_in[3];
  const float* b0        = (const float*)d_in[4];
  const float* Wih1      = (const float*)d_in[5];
  const float* Whh1      = (const float*)d_in[6];
  const float* b1        = (const float*)d_in[7];
  const float* Wout      = (const float*)d_in[8];
  const float* bout      = (const float*)d_in[9];
  float* out = (float*)d_out;

  const size_t gx_bytes = (size_t)DD * TT * NG * sizeof(unsigned short);  // 128 MB
  if (ws_size >= gx_bytes) {
    unsigned short* gxp = (unsigned short*)d_ws;
    gx_kernel<<<dim3(TT / GXTB, DD), dim3(512), 0, stream>>>(shared_in, perdev, Wih0, b0, gxp);
    lstm_pd_kernel<true><<<dim3(DD), dim3(NG), 0, stream>>>(
        shared_in, perdev, Wih0, Whh0, b0, Wih1, Whh1, b1, Wout, bout, gxp, out);
  } else {
    lstm_pd_kernel<false><<<dim3(DD), dim3(NG), 0, stream>>>(
        shared_in, perdev, Wih0, Whh0, b0, Wih1, Whh1, b1, Wout, bout, nullptr, out);
  }
}

// Round 5
// 6901.348 us; speedup vs baseline: 1.2577x; 1.2577x over previous
//
#include <hip/hip_runtime.h>

// Problem constants (match reference)
#define TT 4096   // sequence length (torch "batch" acting as time)
#define SD 64     // shared features
#define PD 8      // per-device features
#define DD 32     // devices
#define HH 128    // hidden
#define NG 512    // 4*H gate rows
#define XD 72     // S+P
#define XPAIRS 36 // packed f16x2 pairs of x
#define WROW 37   // padded row stride (uints) for W_ih0 in LDS (fallback path)
#define GXTB 16   // t-tile of the gx precompute kernel

typedef _Float16 h2 __attribute__((ext_vector_type(2)));
typedef unsigned uv16 __attribute__((ext_vector_type(16)));
typedef unsigned uv4 __attribute__((ext_vector_type(4)));

#if defined(__has_builtin)
#  if __has_builtin(__builtin_amdgcn_fdot2)
#    define USE_DOT2 1
#  endif
#endif

// ---- X-macro machinery: 64 indices, and 16 quads (group, 4 indices) ----
#define LIST64(X) \
  X(0) X(1) X(2) X(3) X(4) X(5) X(6) X(7) \
  X(8) X(9) X(10) X(11) X(12) X(13) X(14) X(15) \
  X(16) X(17) X(18) X(19) X(20) X(21) X(22) X(23) \
  X(24) X(25) X(26) X(27) X(28) X(29) X(30) X(31) \
  X(32) X(33) X(34) X(35) X(36) X(37) X(38) X(39) \
  X(40) X(41) X(42) X(43) X(44) X(45) X(46) X(47) \
  X(48) X(49) X(50) X(51) X(52) X(53) X(54) X(55) \
  X(56) X(57) X(58) X(59) X(60) X(61) X(62) X(63)

#define QUADS16(X) \
  X(0,0,1,2,3)     X(1,4,5,6,7)     X(2,8,9,10,11)   X(3,12,13,14,15) \
  X(4,16,17,18,19) X(5,20,21,22,23) X(6,24,25,26,27) X(7,28,29,30,31) \
  X(8,32,33,34,35) X(9,36,37,38,39) X(10,40,41,42,43) X(11,44,45,46,47) \
  X(12,48,49,50,51) X(13,52,53,54,55) X(14,56,57,58,59) X(15,60,61,62,63)

// pack two floats into one uint of f16x2 (a = low element), RTE
__device__ __forceinline__ unsigned pack_h2(float a, float b) {
  unsigned short ua = __builtin_bit_cast(unsigned short, (_Float16)a);
  unsigned short ub = __builtin_bit_cast(unsigned short, (_Float16)b);
  return ((unsigned)ub << 16) | ua;
}
__device__ __forceinline__ unsigned short f16bits(float a) {
  return __builtin_bit_cast(unsigned short, (_Float16)a);
}
__device__ __forceinline__ float f16val(unsigned short u) {
  return (float)__builtin_bit_cast(_Float16, u);
}

// acc += dot(f16x2 w, f16x2 h), fp32 accumulate (v_dot2_f32_f16)
__device__ __forceinline__ float dot2(unsigned w, unsigned h, float acc) {
#ifdef USE_DOT2
  return __builtin_amdgcn_fdot2(__builtin_bit_cast(h2, w),
                                __builtin_bit_cast(h2, h), acc, false);
#else
  h2 wv = __builtin_bit_cast(h2, w), hv = __builtin_bit_cast(h2, h);
  return __builtin_fmaf((float)wv[1], (float)hv[1],
                        __builtin_fmaf((float)wv[0], (float)hv[0], acc));
#endif
}

__device__ __forceinline__ float fast_sigmoid(float x) {
  return 1.0f / (1.0f + __expf(-x));
}
__device__ __forceinline__ float fast_tanh(float x) {
  return 2.0f / (1.0f + __expf(-2.0f * x)) - 1.0f;
}

// ---------------------------------------------------------------------------
// gx precompute: gx[d][t][g] = f16( b0[d][g] + W_ih0[d][g][:] . x[d][t][:] )
// ---------------------------------------------------------------------------
__global__ __launch_bounds__(512)
void gx_kernel(const float* __restrict__ shared_in,  // [T, S]
               const float* __restrict__ perdev,     // [D, T, P]
               const float* __restrict__ Wih0,       // [D, 4H, S+P]
               const float* __restrict__ b0,         // [D, 4H]
               unsigned short* __restrict__ gx)      // [D, T, 4H] f16
{
  const int d = blockIdx.y;
  const int t0 = blockIdx.x * GXTB;
  const int g = threadIdx.x;

  __shared__ unsigned xs[GXTB * XPAIRS];  // x tile, packed f16x2

  const float* p = Wih0 + (size_t)(d * NG + g) * XD;
  uv16 w0, w1;
  uv4 w2;
#pragma unroll
  for (int j = 0; j < 16; ++j) w0[j] = pack_h2(p[2 * j], p[2 * j + 1]);
#pragma unroll
  for (int j = 0; j < 16; ++j) w1[j] = pack_h2(p[32 + 2 * j], p[33 + 2 * j]);
#pragma unroll
  for (int j = 0; j < 4; ++j) w2[j] = pack_h2(p[64 + 2 * j], p[65 + 2 * j]);
  const float b0g = b0[d * NG + g];

  for (int i = g; i < GXTB * XPAIRS; i += 512) {
    int r = i / XPAIRS, j = i - r * XPAIRS, t = t0 + r;
    float a, b;
    if (j < SD / 2) {
      a = shared_in[t * SD + 2 * j];
      b = shared_in[t * SD + 2 * j + 1];
    } else {
      int k = 2 * (j - SD / 2);
      a = perdev[((size_t)d * TT + t) * PD + k];
      b = perdev[((size_t)d * TT + t) * PD + k + 1];
    }
    xs[i] = pack_h2(a, b);
  }
  __syncthreads();

#define WJ(j) ((j) < 16 ? w0[(j)] : ((j) < 32 ? w1[(j)-16] : w2[(j)-32]))
  for (int tt = 0; tt < GXTB; ++tt) {
    const unsigned* xr = &xs[tt * XPAIRS];
    float a0 = b0g, a1 = 0.f, a2 = 0.f, a3 = 0.f;
#pragma unroll
    for (int j = 0; j < XPAIRS; j += 4) {
      a0 = dot2(WJ(j + 0), xr[j + 0], a0);
      a1 = dot2(WJ(j + 1), xr[j + 1], a1);
      a2 = dot2(WJ(j + 2), xr[j + 2], a2);
      a3 = dot2(WJ(j + 3), xr[j + 3], a3);
    }
    gx[((size_t)d * TT + t0 + tt) * NG + g] = f16bits((a0 + a1) + (a2 + a3));
  }
#undef WJ
}

// ---------------------------------------------------------------------------
// Main recurrence. 192 weight uints held as INDIVIDUAL scalar SSA values
// (no tuples -> no VReg_512 fragmentation, the R2 pathology) combined with
// amdgpu_waves_per_eu(2,2): the EXPLICIT MAX is what raises the RA budget to
// 256 VGPRs (launch_bounds' 2nd arg is only a minimum -> backend kept
// targeting 4 waves/EU = 128 regs and spilled the weights, the R1/R3/R4
// pathology). Both conditions are required simultaneously.
// ---------------------------------------------------------------------------
template <bool PRE>
__global__ __attribute__((amdgpu_flat_work_group_size(512, 512), amdgpu_waves_per_eu(2, 2)))
void lstm_pd_kernel(const float* __restrict__ shared_in,   // [T, S]
                    const float* __restrict__ perdev,      // [D, T, P]
                    const float* __restrict__ Wih0,        // [D, 4H, S+P]
                    const float* __restrict__ Whh0,        // [D, 4H, H]
                    const float* __restrict__ b0,          // [D, 4H]
                    const float* __restrict__ Wih1,        // [D, 4H, H]
                    const float* __restrict__ Whh1,        // [D, 4H, H]
                    const float* __restrict__ b1,          // [D, 4H]
                    const float* __restrict__ Wout,        // [D, H]
                    const float* __restrict__ bout,        // [D]
                    const unsigned short* __restrict__ gx, // [D, T, 4H] f16 (PRE)
                    float* __restrict__ out)               // [T, D]
{
  const int d = blockIdx.x;        // device
  const int g = threadIdx.x;       // gate row 0..511
  const int lane = g & 63;
  const int wave = g >> 6;

  __shared__ float act0_s[NG];
  __shared__ float act1_s[NG];
  __shared__ __align__(16) unsigned h0_s[HH / 2];      // h0 packed f16x2
  __shared__ __align__(16) unsigned h1_s[HH / 2];      // h1 packed f16x2
  __shared__ __align__(16) unsigned x_s[PRE ? 4 : (XPAIRS + 4)];
  __shared__ unsigned wih0_s[PRE ? 1 : (NG * WROW)];
  __shared__ float part_s[2];

  // ---- weight registers: 192 independent scalars ----
#define DW(n) unsigned wa##n, wi##n, wh##n;
  LIST64(DW)
#undef DW
  {
    const float* pa = Whh0 + (size_t)(d * NG + g) * HH;
    const float* pi = Wih1 + (size_t)(d * NG + g) * HH;
    const float* ph = Whh1 + (size_t)(d * NG + g) * HH;
#define SW(n) wa##n = pack_h2(pa[2 * (n)], pa[2 * (n) + 1]); \
              wi##n = pack_h2(pi[2 * (n)], pi[2 * (n) + 1]); \
              wh##n = pack_h2(ph[2 * (n)], ph[2 * (n) + 1]);
    LIST64(SW)
#undef SW
  }

  float b0g = 0.f;
  if (!PRE) {
    const float* p = Wih0 + (size_t)(d * NG + g) * XD;
    for (int j = 0; j < XPAIRS; ++j) wih0_s[g * WROW + j] = pack_h2(p[2 * j], p[2 * j + 1]);
    b0g = b0[d * NG + g];
  }
  const float b1g = b1[d * NG + g];
  const bool is_tanh_gate = ((g >> 7) == 2);  // rows 256..383 = candidate gate
  float c0 = 0.f, c1 = 0.f;
  const float woutu = (g < HH) ? Wout[d * HH + g] : 0.f;
  const float boutd = bout[d];

  if (g < HH / 2) { h0_s[g] = 0u; h1_s[g] = 0u; }

  // prefetch x-path for t=0
  unsigned short gxc = 0, gxn = 0;
  float xa = 0.f, xb = 0.f;
  if (PRE) {
    gxc = gx[((size_t)d * TT + 0) * NG + g];
  } else if (g < XPAIRS) {
    if (g < SD / 2) {
      xa = shared_in[0 * SD + 2 * g];
      xb = shared_in[0 * SD + 2 * g + 1];
    } else {
      int k = 2 * (g - SD / 2);
      xa = perdev[((size_t)d * TT + 0) * PD + k];
      xb = perdev[((size_t)d * TT + 0) * PD + k + 1];
    }
  }

  __syncthreads();

  for (int t = 0; t < TT; ++t) {
    if (!PRE) {
      if (g < XPAIRS) x_s[g] = pack_h2(xa, xb);
      __syncthreads();  // barrier 1 (fallback only)
    }

    // ---- phase 2: gates0[g] = gx + Whh0_row . h0 ----
    float a0, a1 = 0.f, a2 = 0.f, a3 = 0.f;
    if (PRE) {
      a0 = f16val(gxc);
    } else {
      a0 = b0g;
      const unsigned* wrow = &wih0_s[g * WROW];
#pragma unroll
      for (int j = 0; j < XPAIRS; j += 4) {
        a0 = dot2(wrow[j + 0], x_s[j + 0], a0);
        a1 = dot2(wrow[j + 1], x_s[j + 1], a1);
        a2 = dot2(wrow[j + 2], x_s[j + 2], a2);
        a3 = dot2(wrow[j + 3], x_s[j + 3], a3);
      }
    }
    {
      const uint4* h4 = (const uint4*)h0_s;
#define DA(q, n0, n1, n2, n3) { \
      uint4 hv = h4[q]; \
      a0 = dot2(wa##n0, hv.x, a0); a1 = dot2(wa##n1, hv.y, a1); \
      a2 = dot2(wa##n2, hv.z, a2); a3 = dot2(wa##n3, hv.w, a3); }
      QUADS16(DA)
#undef DA
      float pre = (a0 + a1) + (a2 + a3);
      act0_s[g] = is_tanh_gate ? fast_tanh(pre) : fast_sigmoid(pre);
    }
    __syncthreads();  // barrier 2

    // deferred output store for t-1
    if (g == 0 && t > 0) out[(size_t)(t - 1) * DD + d] = part_s[0] + part_s[1] + boutd;

    // prefetch x-path for t+1
    if (PRE) {
      if (t + 1 < TT) gxn = gx[((size_t)d * TT + t + 1) * NG + g];
    } else if (g < XPAIRS && t + 1 < TT) {
      int tn = t + 1;
      if (g < SD / 2) {
        xa = shared_in[tn * SD + 2 * g];
        xb = shared_in[tn * SD + 2 * g + 1];
      } else {
        int k = 2 * (g - SD / 2);
        xa = perdev[((size_t)d * TT + tn) * PD + k];
        xb = perdev[((size_t)d * TT + tn) * PD + k + 1];
      }
    }

    // ---- phase 3: layer-0 cell update (threads 0..127) ----
    if (g < HH) {
      float ig = act0_s[g], fg = act0_s[g + 128], gg = act0_s[g + 256], og = act0_s[g + 384];
      c0 = __builtin_fmaf(fg, c0, ig * gg);
      float h0n = og * fast_tanh(c0);
      ((unsigned short*)h0_s)[g] = f16bits(h0n);
    }
    __syncthreads();  // barrier 3

    // ---- phase 4: gates1[g] = b1 + Wih1_row . h0_new + Whh1_row . h1 ----
    a0 = b1g; a1 = 0.f; a2 = 0.f; a3 = 0.f;
    {
      const uint4* h4 = (const uint4*)h0_s;
#define DI(q, n0, n1, n2, n3) { \
      uint4 hv = h4[q]; \
      a0 = dot2(wi##n0, hv.x, a0); a1 = dot2(wi##n1, hv.y, a1); \
      a2 = dot2(wi##n2, hv.z, a2); a3 = dot2(wi##n3, hv.w, a3); }
      QUADS16(DI)
#undef DI
      const uint4* g4 = (const uint4*)h1_s;
#define DH(q, n0, n1, n2, n3) { \
      uint4 hv = g4[q]; \
      a0 = dot2(wh##n0, hv.x, a0); a1 = dot2(wh##n1, hv.y, a1); \
      a2 = dot2(wh##n2, hv.z, a2); a3 = dot2(wh##n3, hv.w, a3); }
      QUADS16(DH)
#undef DH
      float pre = (a0 + a1) + (a2 + a3);
      act1_s[g] = is_tanh_gate ? fast_tanh(pre) : fast_sigmoid(pre);
    }
    __syncthreads();  // barrier 4

    // ---- phase 5: layer-1 cell update + output partial (threads 0..127) ----
    if (g < HH) {
      float ig = act1_s[g], fg = act1_s[g + 128], gg = act1_s[g + 256], og = act1_s[g + 384];
      c1 = __builtin_fmaf(fg, c1, ig * gg);
      float h1n = og * fast_tanh(c1);
      ((unsigned short*)h1_s)[g] = f16bits(h1n);
      float p = woutu * h1n;
#pragma unroll
      for (int off = 32; off > 0; off >>= 1) p += __shfl_down(p, off, 64);
      if (lane == 0) part_s[wave] = p;
    }
    gxc = gxn;
  }

  __syncthreads();
  if (g == 0) out[(size_t)(TT - 1) * DD + d] = part_s[0] + part_s[1] + boutd;
}

extern "C" void kernel_launch(void* const* d_in, const int* in_sizes, int n_in,
                              void* d_out, int out_size, void* d_ws, size_t ws_size,
                              hipStream_t stream) {
  const float* shared_in = (const float*)d_in[0];
  const float* perdev    = (const float*)d_in[1];
  const float* Wih0      = (const float*)d_in[2];
  const float* Whh0      = (const float*)d_in[3];
  const float* b0        = (const float*)d_in[4];
  const float* Wih1      = (const float*)d_in[5];
  const float* Whh1      = (const float*)d_in[6];
  const float* b1        = (const float*)d_in[7];
  const float* Wout      = (const float*)d_in[8];
  const float* bout      = (const float*)d_in[9];
  float* out = (float*)d_out;

  const size_t gx_bytes = (size_t)DD * TT * NG * sizeof(unsigned short);  // 128 MB
  if (ws_size >= gx_bytes) {
    unsigned short* gxp = (unsigned short*)d_ws;
    gx_kernel<<<dim3(TT / GXTB, DD), dim3(512), 0, stream>>>(shared_in, perdev, Wih0, b0, gxp);
    lstm_pd_kernel<true><<<dim3(DD), dim3(NG), 0, stream>>>(
        shared_in, perdev, Wih0, Whh0, b0, Wih1, Whh1, b1, Wout, bout, gxp, out);
  } else {
    lstm_pd_kernel<false><<<dim3(DD), dim3(NG), 0, stream>>>(
        shared_in, perdev, Wih0, Whh0, b0, Wih1, Whh1, b1, Wout, bout, nullptr, out);
  }
}